// Round 10
// baseline (184.039 us; speedup 1.0000x reference)
//
#include <hip/hip_runtime.h>

// Cholesky-from-partial-correlations.
//   out[b,i,j] = z_j * sqrt( prod_{k<j} (1 - z_k^2) )  for j < i;  1 on diag; 0 above.
// Persistent-wave shape: 8192 co-resident waves, each owning 16 rows
// (b = b0 + 32k, i wave-constant) with a 1-deep load pipeline.
// One dwordx4 load + one dwordx4 store per row per lane.
// R9 bugfix: boundary fallback now loads ALL FOUR components (clamped);
// lane 63's clamped read of the last row is masked by j<i, lanes 0..62
// get their real z values (R9 zeroed every 4th element of the last row).

#define SIZE 256
#define BATCH 512
#define M (SIZE * (SIZE - 1) / 2)   // 32640
#define TOTAL (BATCH * M)           // 16711680
#define NWAVES 8192                 // 2048 blocks * 4 waves
#define ROWS_PER_WAVE 16            // 131072 / 8192

typedef float f4u __attribute__((ext_vector_type(4), aligned(4)));

template <int CTRL, int ROW_MASK>
__device__ __forceinline__ float scan_mul(float p) {
    int sh = __builtin_amdgcn_update_dpp(
        __builtin_bit_cast(int, 1.0f),
        __builtin_bit_cast(int, p),
        CTRL, ROW_MASK, 0xF, false);
    return p * __builtin_bit_cast(float, sh);
}

__device__ __forceinline__ float excl_shift_one(float p) {
    int r = __builtin_amdgcn_update_dpp(
        __builtin_bit_cast(int, 1.0f),
        __builtin_bit_cast(int, p),
        0x138 /* wave_shr:1 */, 0xF, 0xF, false);
    return __builtin_bit_cast(float, r);
}

__device__ __forceinline__ f4u load_chunk(const float* __restrict__ vec,
                                          int row_off, int j0) {
    const float* __restrict__ s = vec + row_off;
    f4u zv;
    if (row_off <= TOTAL - 256) {            // wave-uniform; false only for the
        zv = *(const f4u*)(s + j0);          // globally-last row (b=511,i=255)
    } else {
        const int mi = TOTAL - 1 - row_off;  // = 254 for the last row
        zv.x = s[j0     < mi ? j0     : mi];
        zv.y = s[j0 + 1 < mi ? j0 + 1 : mi];
        zv.z = s[j0 + 2 < mi ? j0 + 2 : mi];
        zv.w = s[j0 + 3 < mi ? j0 + 3 : mi]; // clamped read, masked by j<i below
    }
    return zv;
}

__global__ __launch_bounds__(256, 8) void chol_from_z_kernel(
    const float* __restrict__ vec, float* __restrict__ out) {
    const int lane = threadIdx.x & 63;
    const int wib = __builtin_amdgcn_readfirstlane((int)threadIdx.x >> 6);
    const int wave_id = (int)blockIdx.x * 4 + wib;   // 0 .. 8191
    const int i  = wave_id & 255;                    // row-in-batch: wave-constant
    const int b0 = wave_id >> 8;                     // base batch: 0..31
    const int tri = (i * (i - 1)) >> 1;
    const int j0 = lane << 2;

    // prologue: load k=0
    f4u zv = load_chunk(vec, b0 * M + tri, j0);

    for (int k = 0; k < ROWS_PER_WAVE; ++k) {
        const int b = b0 + (k << 5);
        // pipeline: issue next row's load before computing this one
        const int bn = (k == ROWS_PER_WAVE - 1) ? b0 : b + 32;  // last: dummy reload
        f4u znext = load_chunk(vec, bn * M + tri, j0);

        const float z0 = (j0     < i) ? zv.x : 0.f;
        const float z1 = (j0 + 1 < i) ? zv.y : 0.f;
        const float z2 = (j0 + 2 < i) ? zv.z : 0.f;
        const float z3 = (j0 + 3 < i) ? zv.w : 0.f;

        const float t0 = 1.f - z0 * z0;
        const float t1 = 1.f - z1 * z1;
        const float t2 = 1.f - z2 * z2;
        const float t3 = 1.f - z3 * z3;

        float p = (t0 * t1) * (t2 * t3);
        p = scan_mul<0x111, 0xF>(p);                 // row_shr:1
        p = scan_mul<0x112, 0xF>(p);                 // row_shr:2
        p = scan_mul<0x114, 0xF>(p);                 // row_shr:4
        p = scan_mul<0x118, 0xF>(p);                 // row_shr:8
        if (i >= 64)  p = scan_mul<0x142, 0xA>(p);   // row_bcast:15
        if (i >= 128) p = scan_mul<0x143, 0xC>(p);   // row_bcast:31

        float run = excl_shift_one(p);

        f4u o;
        o.x = (j0     == i) ? 1.f : z0 * __builtin_amdgcn_sqrtf(run); run *= t0;
        o.y = (j0 + 1 == i) ? 1.f : z1 * __builtin_amdgcn_sqrtf(run); run *= t1;
        o.z = (j0 + 2 == i) ? 1.f : z2 * __builtin_amdgcn_sqrtf(run); run *= t2;
        o.w = (j0 + 3 == i) ? 1.f : z3 * __builtin_amdgcn_sqrtf(run);

        float* __restrict__ dst = out + (((size_t)b << 8) + (size_t)i) * SIZE + j0;
        *(f4u*)dst = o;

        zv = znext;
    }
}

extern "C" void kernel_launch(void* const* d_in, const int* in_sizes, int n_in,
                              void* d_out, int out_size, void* d_ws, size_t ws_size,
                              hipStream_t stream) {
    const float* vec = (const float*)d_in[0];
    float* out = (float*)d_out;
    chol_from_z_kernel<<<NWAVES / 4, 256, 0, stream>>>(vec, out);
}

// Round 11
// 178.877 us; speedup vs baseline: 1.0289x; 1.0289x over previous
//
#include <hip/hip_runtime.h>

// Cholesky-from-partial-correlations.
//   out[b,i,j] = z_j * sqrt( prod_{k<j} (1 - z_k^2) )  for j < i;  1 on diag; 0 above.
// R7 structure (best: one wave per row, max TLP, 1 dwordx4 load + 1 dwordx4
// store per lane) repacked into 1024-thread blocks: same 131072 one-shot
// waves, 4x fewer block dispatch/teardown events. Tests whether block-
// granularity churn is the unexplained ~20 us term.

#define SIZE 256
#define BATCH 512
#define M (SIZE * (SIZE - 1) / 2)   // 32640
#define TOTAL (BATCH * M)           // 16711680

typedef float f4u __attribute__((ext_vector_type(4), aligned(4)));

// p *= dpp_shifted(p); invalid lanes contribute 1.0f (identity) via `old`
template <int CTRL, int ROW_MASK>
__device__ __forceinline__ float scan_mul(float p) {
    int sh = __builtin_amdgcn_update_dpp(
        __builtin_bit_cast(int, 1.0f),
        __builtin_bit_cast(int, p),
        CTRL, ROW_MASK, 0xF, false);
    return p * __builtin_bit_cast(float, sh);
}

// whole-wave shift right by 1; lane 0 gets 1.0f (exclusive-scan carry-in)
__device__ __forceinline__ float excl_shift_one(float p) {
    int r = __builtin_amdgcn_update_dpp(
        __builtin_bit_cast(int, 1.0f),
        __builtin_bit_cast(int, p),
        0x138 /* wave_shr:1 */, 0xF, 0xF, false);
    return __builtin_bit_cast(float, r);
}

__global__ __launch_bounds__(1024) void chol_from_z_kernel(
    const float* __restrict__ vec, float* __restrict__ out) {
    const int lane = threadIdx.x & 63;
    const int wib = __builtin_amdgcn_readfirstlane((int)threadIdx.x >> 6);
    const int wave = (int)blockIdx.x * 16 + wib;  // 0 .. BATCH*SIZE-1
    const int b = wave >> 8;                      // batch
    const int i = wave & 255;                     // row
    const int row_off = b * M + ((i * (i - 1)) >> 1);
    const float* __restrict__ s = vec + row_off;
    float* __restrict__ dst = out + ((size_t)wave << 8);
    const int j0 = lane << 2;

    // ---- single vector load per lane (garbage past row end is masked) ----
    const int maxidx = (TOTAL - 1) - row_off;     // last valid index in s[]
    f4u zv;
    if (j0 + 3 <= maxidx) {                       // per-lane; false only for lane 63
        zv = *(const f4u*)(s + j0);               // of the globally-last row
    } else {
        zv.x = s[j0]; zv.y = s[j0 + 1]; zv.z = s[j0 + 2]; zv.w = 0.f;
    }

    // mask to strictly-lower region
    const float z0 = (j0     < i) ? zv.x : 0.f;
    const float z1 = (j0 + 1 < i) ? zv.y : 0.f;
    const float z2 = (j0 + 2 < i) ? zv.z : 0.f;
    const float z3 = (j0 + 3 < i) ? zv.w : 0.f;

    const float t0 = 1.f - z0 * z0;
    const float t1 = 1.f - z1 * z1;
    const float t2 = 1.f - z2 * z2;
    const float t3 = 1.f - z3 * z3;

    float p = (t0 * t1) * (t2 * t3);

    // wave64 inclusive prefix product — up to 6 VALU DPP steps
    p = scan_mul<0x111, 0xF>(p);                  // row_shr:1
    p = scan_mul<0x112, 0xF>(p);                  // row_shr:2
    p = scan_mul<0x114, 0xF>(p);                  // row_shr:4
    p = scan_mul<0x118, 0xF>(p);                  // row_shr:8
    if (i >= 64)  p = scan_mul<0x142, 0xA>(p);    // row_bcast:15 -> rows 1,3
    if (i >= 128) p = scan_mul<0x143, 0xC>(p);    // row_bcast:31 -> rows 2,3

    float run = excl_shift_one(p);

    f4u o;
    o.x = (j0     == i) ? 1.f : z0 * __builtin_amdgcn_sqrtf(run); run *= t0;
    o.y = (j0 + 1 == i) ? 1.f : z1 * __builtin_amdgcn_sqrtf(run); run *= t1;
    o.z = (j0 + 2 == i) ? 1.f : z2 * __builtin_amdgcn_sqrtf(run); run *= t2;
    o.w = (j0 + 3 == i) ? 1.f : z3 * __builtin_amdgcn_sqrtf(run);

    *(f4u*)(dst + j0) = o;        // dst 1 KiB-aligned, j0*4 is 16B multiple
}

extern "C" void kernel_launch(void* const* d_in, const int* in_sizes, int n_in,
                              void* d_out, int out_size, void* d_ws, size_t ws_size,
                              hipStream_t stream) {
    const float* vec = (const float*)d_in[0];
    float* out = (float*)d_out;
    const int n_waves = BATCH * SIZE;             // 131072 rows, 1 wave each
    const int blocks = n_waves / 16;              // 8192 blocks of 1024 threads
    chol_from_z_kernel<<<blocks, 1024, 0, stream>>>(vec, out);
}

// Round 12
// 175.585 us; speedup vs baseline: 1.0481x; 1.0188x over previous
//
#include <hip/hip_runtime.h>

// Cholesky-from-partial-correlations.
//   out[b,i,j] = z_j * sqrt( prod_{k<j} (1 - z_k^2) )  for j < i;  1 on diag; 0 above.
// R7 structure (one wave per row, 256-thr blocks, DPP scan) + PREDICATED
// LOADS: lanes with j0 >= i issue no load (exec-masked), halving read
// traffic 134->67 MB. Kernel was at ~89% of the copy ceiling for the bytes
// it issued; this cuts the bytes.

#define SIZE 256
#define BATCH 512
#define M (SIZE * (SIZE - 1) / 2)   // 32640
#define TOTAL (BATCH * M)           // 16711680

typedef float f4u __attribute__((ext_vector_type(4), aligned(4)));

// p *= dpp_shifted(p); invalid lanes contribute 1.0f (identity) via `old`
template <int CTRL, int ROW_MASK>
__device__ __forceinline__ float scan_mul(float p) {
    int sh = __builtin_amdgcn_update_dpp(
        __builtin_bit_cast(int, 1.0f),
        __builtin_bit_cast(int, p),
        CTRL, ROW_MASK, 0xF, false);
    return p * __builtin_bit_cast(float, sh);
}

// whole-wave shift right by 1; lane 0 gets 1.0f (exclusive-scan carry-in)
__device__ __forceinline__ float excl_shift_one(float p) {
    int r = __builtin_amdgcn_update_dpp(
        __builtin_bit_cast(int, 1.0f),
        __builtin_bit_cast(int, p),
        0x138 /* wave_shr:1 */, 0xF, 0xF, false);
    return __builtin_bit_cast(float, r);
}

__global__ __launch_bounds__(256) void chol_from_z_kernel(
    const float* __restrict__ vec, float* __restrict__ out) {
    const int lane = threadIdx.x & 63;
    const int wib = __builtin_amdgcn_readfirstlane((int)threadIdx.x >> 6);
    const int wave = (int)blockIdx.x * 4 + wib;   // 0 .. BATCH*SIZE-1
    const int b = wave >> 8;                      // batch
    const int i = wave & 255;                     // row
    const int row_off = b * M + ((i * (i - 1)) >> 1);
    const float* __restrict__ s = vec + row_off;
    float* __restrict__ dst = out + ((size_t)wave << 8);
    const int j0 = lane << 2;

    // ---- predicated vector load: only lanes intersecting the strictly-lower
    // region issue a load; others contribute identity (z=0). Halves read bytes.
    const int maxidx = (TOTAL - 1) - row_off;     // last valid index in s[]
    f4u zv = {0.f, 0.f, 0.f, 0.f};
    if (j0 < i) {
        if (j0 + 3 <= maxidx) {                   // false only for lane 63 of the
            zv = *(const f4u*)(s + j0);           // globally-last row (b=511,i=255)
        } else {
            zv.x = s[j0]; zv.y = s[j0 + 1]; zv.z = s[j0 + 2]; zv.w = 0.f;
        }
    }

    // mask to strictly-lower region
    const float z0 = (j0     < i) ? zv.x : 0.f;
    const float z1 = (j0 + 1 < i) ? zv.y : 0.f;
    const float z2 = (j0 + 2 < i) ? zv.z : 0.f;
    const float z3 = (j0 + 3 < i) ? zv.w : 0.f;

    const float t0 = 1.f - z0 * z0;
    const float t1 = 1.f - z1 * z1;
    const float t2 = 1.f - z2 * z2;
    const float t3 = 1.f - z3 * z3;

    float p = (t0 * t1) * (t2 * t3);

    // wave64 inclusive prefix product — up to 6 VALU DPP steps
    p = scan_mul<0x111, 0xF>(p);                  // row_shr:1
    p = scan_mul<0x112, 0xF>(p);                  // row_shr:2
    p = scan_mul<0x114, 0xF>(p);                  // row_shr:4
    p = scan_mul<0x118, 0xF>(p);                  // row_shr:8
    if (i >= 64)  p = scan_mul<0x142, 0xA>(p);    // row_bcast:15 -> rows 1,3
    if (i >= 128) p = scan_mul<0x143, 0xC>(p);    // row_bcast:31 -> rows 2,3

    float run = excl_shift_one(p);

    f4u o;
    o.x = (j0     == i) ? 1.f : z0 * __builtin_amdgcn_sqrtf(run); run *= t0;
    o.y = (j0 + 1 == i) ? 1.f : z1 * __builtin_amdgcn_sqrtf(run); run *= t1;
    o.z = (j0 + 2 == i) ? 1.f : z2 * __builtin_amdgcn_sqrtf(run); run *= t2;
    o.w = (j0 + 3 == i) ? 1.f : z3 * __builtin_amdgcn_sqrtf(run);

    *(f4u*)(dst + j0) = o;        // dst 1 KiB-aligned, j0*4 is 16B multiple
}

extern "C" void kernel_launch(void* const* d_in, const int* in_sizes, int n_in,
                              void* d_out, int out_size, void* d_ws, size_t ws_size,
                              hipStream_t stream) {
    const float* vec = (const float*)d_in[0];
    float* out = (float*)d_out;
    const int n_waves = BATCH * SIZE;             // 131072 rows, 1 wave each
    const int blocks = n_waves / 4;               // 4 waves (256 thr) per block
    chol_from_z_kernel<<<blocks, 256, 0, stream>>>(vec, out);
}